// Round 16
// baseline (197.870 us; speedup 1.0000x reference)
//
#include <hip/hip_runtime.h>

#define SEQ    4096
#define NB     32
#define NC     128        // chunks per sequence
#define CSTEPS 32         // steps per chunk

typedef float f32x4 __attribute__((ext_vector_type(4)));

// ws layout (floats):
//  BD  [32][4096][16]         @ 0
//  CD  [32][4096][16]         @ 2097152
//  XP  [32][4096][4]          @ 4194304   (xp rows 16..19, feeds dt)
//  Pp  float2 [32][128][1024] @ 4718592   (P, p per cell/chunk)
//  Hin [32][128][1024]        @ 13107200  (carry-in h, compact)
// total 17301504 floats = 69.2 MB

__device__ __forceinline__ void async_copy16(const float* g, float* l) {
  __builtin_amdgcn_global_load_lds(
      (const __attribute__((address_space(1))) void*)g,
      (__attribute__((address_space(3))) void*)l, 16, 0, 0);
}

// quad_perm DPP adds: lane i reads lane (i&~3)|perm[i&3]
__device__ __forceinline__ float qp_add_b1(float s) {
  return s + __int_as_float(__builtin_amdgcn_update_dpp(
                 0, __float_as_int(s), 0xB1, 0xf, 0xf, false));
}
__device__ __forceinline__ float qp_add_4e(float s) {
  return s + __int_as_float(__builtin_amdgcn_update_dpp(
                 0, __float_as_int(s), 0x4E, 0xf, 0xf, false));
}

// ------------- Phase 1: projections + per-chunk aggregates (fused) ---------
__global__ __launch_bounds__(256, 4) void ssm_prep(
    const float* __restrict__ x, const float* __restrict__ Wx,
    const float* __restrict__ bx, const float* __restrict__ Wdt,
    const float* __restrict__ bdt, const float* __restrict__ A_log,
    float* __restrict__ ws, float2* __restrict__ Pp) {
  __shared__ float dts[64 * 64];   // [t][d]
  __shared__ float xds[64 * 64];   // [t][d] = x*dt
  __shared__ float Bs[64 * 16];    // [t][n]
  const int tid = threadIdx.x;
  const int w = tid >> 6;
  const int l = tid & 63;
  const int b = blockIdx.x >> 6;
  const int t0 = (blockIdx.x & 63) << 6;

  const int lr = l < 36 ? l : 35;
  float wrow[64];
#pragma unroll
  for (int i = 0; i < 16; ++i) {
    const float4 v = ((const float4*)(Wx + lr * 64))[i];
    wrow[4 * i + 0] = v.x; wrow[4 * i + 1] = v.y;
    wrow[4 * i + 2] = v.z; wrow[4 * i + 3] = v.w;
  }
  const float bxv = bx[lr];
  const float4 wdtv = ((const float4*)Wdt)[l];
  const float bdtv = bdt[l];

  float xiv[16];
#pragma unroll
  for (int i = 0; i < 16; ++i)
    xiv[i] = x[((size_t)b * SEQ + (t0 + (w << 4) + i)) * 64 + l];

  float* BD = ws;
  float* CD = ws + 2097152;
  float* XP = ws + 4194304;

#pragma unroll
  for (int i = 0; i < 16; ++i) {
    const int tl = (w << 4) + i;          // local t
    const int t  = t0 + tl;
    const int xibits = __float_as_int(xiv[i]);
    float acc0 = bxv, acc1 = 0.f;
#pragma unroll
    for (int dj = 0; dj < 64; dj += 2) {
      acc0 = fmaf(wrow[dj],     __int_as_float(__builtin_amdgcn_readlane(xibits, dj)),     acc0);
      acc1 = fmaf(wrow[dj + 1], __int_as_float(__builtin_amdgcn_readlane(xibits, dj + 1)), acc1);
    }
    const float acc = acc0 + acc1;       // xp[l], valid l<36
    const int ab = __float_as_int(acc);
    float dtv = bdtv;
    dtv = fmaf(wdtv.x, __int_as_float(__builtin_amdgcn_readlane(ab, 16)), dtv);
    dtv = fmaf(wdtv.y, __int_as_float(__builtin_amdgcn_readlane(ab, 17)), dtv);
    dtv = fmaf(wdtv.z, __int_as_float(__builtin_amdgcn_readlane(ab, 18)), dtv);
    dtv = fmaf(wdtv.w, __int_as_float(__builtin_amdgcn_readlane(ab, 19)), dtv);
    dts[tl * 64 + l] = dtv;
    xds[tl * 64 + l] = xiv[i] * dtv;
    if (l < 16) {
      BD[((size_t)b * SEQ + t) * 16 + l] = acc;
      Bs[tl * 16 + l] = acc;
    } else if (l < 20) {
      XP[((size_t)b * SEQ + t) * 4 + (l - 16)] = acc;
    } else if (l < 36) {
      CD[((size_t)b * SEQ + t) * 16 + (l - 20)] = acc;
    }
  }
  __syncthreads();

  // Phase B: two 32-step chunk aggregates. thread -> d = tid>>2, n0=4*(tid&3)
  const int d  = tid >> 2;
  const int n0 = (tid & 3) << 2;
  float Av4[4];
  {
    const float4 a = *(const float4*)(A_log + d * 16 + n0);
    Av4[0] = -expf(a.x); Av4[1] = -expf(a.y);
    Av4[2] = -expf(a.z); Av4[3] = -expf(a.w);
  }
  float2* PpB = Pp + (size_t)b * (128 * 1024);
#pragma unroll
  for (int cl = 0; cl < 2; ++cl) {
    float P0 = 1.f, P1 = 1.f, P2 = 1.f, P3 = 1.f;
    float q0 = 0.f, q1 = 0.f, q2 = 0.f, q3 = 0.f;
#pragma unroll
    for (int s = 0; s < 32; ++s) {
      const int tl = (cl << 5) + s;
      const float dtv = dts[tl * 64 + d];
      const float xdt = xds[tl * 64 + d];
      const float4 Bq = *(const float4*)(&Bs[tl * 16 + n0]);
      float dA;
      dA = dtv * Av4[0]; q0 = fmaf(q0, dA, xdt * Bq.x); P0 *= dA;
      dA = dtv * Av4[1]; q1 = fmaf(q1, dA, xdt * Bq.y); P1 *= dA;
      dA = dtv * Av4[2]; q2 = fmaf(q2, dA, xdt * Bq.z); P2 *= dA;
      dA = dtv * Av4[3]; q3 = fmaf(q3, dA, xdt * Bq.w); P3 *= dA;
    }
    const int c = ((blockIdx.x & 63) << 1) + cl;
    float4* dst = (float4*)(PpB + (size_t)c * 1024 + d * 16 + n0);
    dst[0] = make_float4(P0, q0, P1, q1);
    dst[1] = make_float4(P2, q2, P3, q3);
  }
}

// ------------- Phase 2: serial carry; compact Hin ---------------------------
__global__ __launch_bounds__(256) void ssm_carry(const float2* __restrict__ Pp,
                                                 float* __restrict__ Hin) {
  const int b = blockIdx.x >> 2;
  const int cell = ((blockIdx.x & 3) << 8) + threadIdx.x;
  const float2* base = Pp + (size_t)b * (128 * 1024) + cell;
  float* hout = Hin + (size_t)b * (128 * 1024) + cell;
  float H = 0.f;
#pragma unroll
  for (int g = 0; g < 8; ++g) {
    float2 v[16];
#pragma unroll
    for (int j = 0; j < 16; ++j) v[j] = base[(size_t)(g * 16 + j) * 1024];
#pragma unroll
    for (int j = 0; j < 16; ++j) {
      hout[(size_t)(g * 16 + j) * 1024] = H;
      H = fmaf(v[j].x, H, v[j].y);
    }
  }
}

// ------------- Phase 3: scan; dt recomputed from XP; normal stores ---------
__global__ __launch_bounds__(256, 8) void ssm_scan(
    const float* __restrict__ ws, const float* __restrict__ x,
    const float* __restrict__ Wdt, const float* __restrict__ bdt,
    const float* __restrict__ A_log, const float* __restrict__ Dp,
    float* __restrict__ out, float* __restrict__ hidden) {
  __shared__ __align__(16) float x_lds[32 * 64];   // [t][d] 8 KB
  __shared__ __align__(16) float Bs[32 * 16];      // [t][n] 2 KB
  __shared__ __align__(16) float Cs[32 * 16];      // [t][n] 2 KB
  __shared__ __align__(16) float xq_lds[32 * 4];   // [t][r] 0.5 KB
  const int tid  = threadIdx.x;
  const int w    = tid >> 6;            // wave = d-quarter dq
  const int lane = tid & 63;
  const int b  = blockIdx.x >> 7;
  const int c  = blockIdx.x & 127;
  const int t0 = c << 5;
  const int dl = lane >> 2;             // d within quarter
  const int nq = lane & 3;              // n-quad
  const int d  = (w << 4) + dl;

  // ---- stage: x (each wave stages its 8-t slice); B,C split; XP by wave0 --
  const float* xg = x + ((size_t)b * SEQ + t0 + (w << 3)) * 64;
  const int srcoff = (lane >> 4) * 64 + (lane & 15) * 4;  // t-row + 16B piece
#pragma unroll
  for (int k = 0; k < 2; ++k)
    async_copy16(xg + k * 256 + srcoff, x_lds + ((w << 3) + (k << 2)) * 64 + lane * 4);
  const float* Bg  = ws +           ((size_t)b * SEQ + t0) * 16;
  const float* Cg  = ws + 2097152 + ((size_t)b * SEQ + t0) * 16;
  const float* XPg = ws + 4194304 + ((size_t)b * SEQ + t0) * 4;
  if (w == 0)      async_copy16(Bg + lane * 4, Bs + lane * 4);
  else if (w == 1) async_copy16(Bg + 256 + lane * 4, Bs + 256 + lane * 4);
  else if (w == 2) async_copy16(Cg + lane * 4, Cs + lane * 4);
  else             async_copy16(Cg + 256 + lane * 4, Cs + 256 + lane * 4);
  if (tid < 32)    async_copy16(XPg + tid * 4, xq_lds + tid * 4);

  float Av[4];
  {
    const float4 a = *(const float4*)(A_log + d * 16 + (nq << 2));
    Av[0] = -expf(a.x); Av[1] = -expf(a.y);
    Av[2] = -expf(a.z); Av[3] = -expf(a.w);
  }
  const float Dpv = Dp[d];
  const float4 wdtv = ((const float4*)Wdt)[d];
  const float bdtv = bdt[d];

  float h[4];
  {
    const f32x4 v = *(const f32x4*)(ws + 13107200 +
        ((size_t)b * 128 + c) * 1024 + d * 16 + (nq << 2));
    h[0] = v.x; h[1] = v.y; h[2] = v.z; h[3] = v.w;
  }

  // lane writes 16B at byte offset 16*lane -> wave-step writes contiguous 1KB
  float* hidp = hidden + ((size_t)b * SEQ + t0) * 1024 + (w << 8) + (lane << 2);
  float* outp = out + ((size_t)b * SEQ + t0) * 64 + d;

  asm volatile("s_waitcnt vmcnt(0)" ::: "memory");
  __syncthreads();

  // ---- body: LDS reads + VALU + normal stores (no global loads/vmcnt) ----
  for (int T = 0; T < CSTEPS; T += 8) {
    float x8[8], dt8[8];
#pragma unroll
    for (int j = 0; j < 8; ++j) {
      x8[j] = x_lds[(T + j) * 64 + d];
      const f32x4 xp = *(const f32x4*)(xq_lds + (T + j) * 4);
      float dtv = bdtv;
      dtv = fmaf(wdtv.x, xp.x, dtv);
      dtv = fmaf(wdtv.y, xp.y, dtv);
      dtv = fmaf(wdtv.z, xp.z, dtv);
      dtv = fmaf(wdtv.w, xp.w, dtv);
      dt8[j] = dtv;
    }
#pragma unroll
    for (int j = 0; j < 8; ++j) {
      const int t = T + j;
      const float dtv = dt8[j];
      const float xv  = x8[j];
      const float xd  = xv * dtv;
      const float4 Bq = *(const float4*)(Bs + t * 16 + (nq << 2));
      const float4 Cq = *(const float4*)(Cs + t * 16 + (nq << 2));
      float y, hv;
      hv = __builtin_amdgcn_fmed3f(fmaf(h[0], dtv * Av[0], xd * Bq.x), -1e6f, 1e6f);
      h[0] = hv; y = hv * Cq.x;
      hv = __builtin_amdgcn_fmed3f(fmaf(h[1], dtv * Av[1], xd * Bq.y), -1e6f, 1e6f);
      h[1] = hv; y = fmaf(hv, Cq.y, y);
      hv = __builtin_amdgcn_fmed3f(fmaf(h[2], dtv * Av[2], xd * Bq.z), -1e6f, 1e6f);
      h[2] = hv; y = fmaf(hv, Cq.z, y);
      hv = __builtin_amdgcn_fmed3f(fmaf(h[3], dtv * Av[3], xd * Bq.w), -1e6f, 1e6f);
      h[3] = hv; y = fmaf(hv, Cq.w, y);
      *(float4*)(hidp + (size_t)t * 1024) = make_float4(h[0], h[1], h[2], h[3]);
      y = qp_add_b1(y);   // quad_perm [1,0,3,2]
      y = qp_add_4e(y);   // quad_perm [2,3,0,1] -> full quad sum
      if (nq == 0) outp[(size_t)t * 64] = fmaf(Dpv, xv, y);
    }
  }
}

extern "C" void kernel_launch(void* const* d_in, const int* in_sizes, int n_in,
                              void* d_out, int out_size, void* d_ws, size_t ws_size,
                              hipStream_t stream) {
  (void)in_sizes; (void)n_in; (void)out_size; (void)ws_size;
  const float* x     = (const float*)d_in[0];
  const float* Wx    = (const float*)d_in[1];
  const float* bx    = (const float*)d_in[2];
  const float* Wdt   = (const float*)d_in[3];
  const float* bdt   = (const float*)d_in[4];
  const float* A_log = (const float*)d_in[5];
  const float* Dp    = (const float*)d_in[6];
  float* out    = (float*)d_out;
  float* hidden = out + (size_t)NB * SEQ * 64;
  float* ws     = (float*)d_ws;
  float2* Pp    = (float2*)(ws + 4718592);
  float*  Hin   = ws + 13107200;

  ssm_prep<<<dim3(2048), dim3(256), 0, stream>>>(x, Wx, bx, Wdt, bdt, A_log, ws, Pp);
  ssm_carry<<<dim3(128), dim3(256), 0, stream>>>(Pp, Hin);
  ssm_scan<<<dim3(4096), dim3(256), 0, stream>>>(ws, x, Wdt, bdt, A_log, Dp, out, hidden);
}

// Round 17
// 166.112 us; speedup vs baseline: 1.1912x; 1.1912x over previous
//
#include <hip/hip_runtime.h>

#define SEQ    4096
#define NB     32
#define NC     64         // chunks per sequence
#define CSTEPS 64         // steps per chunk

typedef float f32x4 __attribute__((ext_vector_type(4)));

// ws layout (floats):
//  BD  [32][4096][16]        @ 0
//  CD  [32][4096][16]        @ 2097152
//  XP  [32][4096][4]         @ 4194304   (xp rows 16..19, feeds dt)
//  Pp  float2 [32][64][1024] @ 4718592   (P, p per cell/chunk)
//  Hin [32][64][1024]        @ 8912896   (carry-in h, compact)
// total 11010048 floats = 44 MB

__device__ __forceinline__ void async_copy16(const float* g, float* l) {
  __builtin_amdgcn_global_load_lds(
      (const __attribute__((address_space(1))) void*)g,
      (__attribute__((address_space(3))) void*)l, 16, 0, 0);
}

// quad_perm DPP adds: lane i reads lane (i&~3)|perm[i&3]
__device__ __forceinline__ float qp_add_b1(float s) {
  return s + __int_as_float(__builtin_amdgcn_update_dpp(
                 0, __float_as_int(s), 0xB1, 0xf, 0xf, false));
}
__device__ __forceinline__ float qp_add_4e(float s) {
  return s + __int_as_float(__builtin_amdgcn_update_dpp(
                 0, __float_as_int(s), 0x4E, 0xf, 0xf, false));
}

// ------------- Phase 1: projections + per-chunk aggregates (fused) ---------
__global__ __launch_bounds__(256, 4) void ssm_prep(
    const float* __restrict__ x, const float* __restrict__ Wx,
    const float* __restrict__ bx, const float* __restrict__ Wdt,
    const float* __restrict__ bdt, const float* __restrict__ A_log,
    float* __restrict__ ws, float2* __restrict__ Pp) {
  __shared__ float dts[64 * 64];   // [t][d]
  __shared__ float xds[64 * 64];   // [t][d] = x*dt
  __shared__ float Bs[64 * 16];    // [t][n]
  const int tid = threadIdx.x;
  const int w = tid >> 6;
  const int l = tid & 63;
  const int b = blockIdx.x >> 6;
  const int t0 = (blockIdx.x & 63) << 6;

  const int lr = l < 36 ? l : 35;
  float wrow[64];
#pragma unroll
  for (int i = 0; i < 16; ++i) {
    const float4 v = ((const float4*)(Wx + lr * 64))[i];
    wrow[4 * i + 0] = v.x; wrow[4 * i + 1] = v.y;
    wrow[4 * i + 2] = v.z; wrow[4 * i + 3] = v.w;
  }
  const float bxv = bx[lr];
  const float4 wdtv = ((const float4*)Wdt)[l];
  const float bdtv = bdt[l];

  float xiv[16];
#pragma unroll
  for (int i = 0; i < 16; ++i)
    xiv[i] = x[((size_t)b * SEQ + (t0 + (w << 4) + i)) * 64 + l];

  float* BD = ws;
  float* CD = ws + 2097152;
  float* XP = ws + 4194304;

#pragma unroll
  for (int i = 0; i < 16; ++i) {
    const int tl = (w << 4) + i;          // local t
    const int t  = t0 + tl;
    const int xibits = __float_as_int(xiv[i]);
    float acc0 = bxv, acc1 = 0.f;
#pragma unroll
    for (int dj = 0; dj < 64; dj += 2) {
      acc0 = fmaf(wrow[dj],     __int_as_float(__builtin_amdgcn_readlane(xibits, dj)),     acc0);
      acc1 = fmaf(wrow[dj + 1], __int_as_float(__builtin_amdgcn_readlane(xibits, dj + 1)), acc1);
    }
    const float acc = acc0 + acc1;       // xp[l], valid l<36
    const int ab = __float_as_int(acc);
    float dtv = bdtv;
    dtv = fmaf(wdtv.x, __int_as_float(__builtin_amdgcn_readlane(ab, 16)), dtv);
    dtv = fmaf(wdtv.y, __int_as_float(__builtin_amdgcn_readlane(ab, 17)), dtv);
    dtv = fmaf(wdtv.z, __int_as_float(__builtin_amdgcn_readlane(ab, 18)), dtv);
    dtv = fmaf(wdtv.w, __int_as_float(__builtin_amdgcn_readlane(ab, 19)), dtv);
    dts[tl * 64 + l] = dtv;
    xds[tl * 64 + l] = xiv[i] * dtv;
    if (l < 16) {
      BD[((size_t)b * SEQ + t) * 16 + l] = acc;
      Bs[tl * 16 + l] = acc;
    } else if (l < 20) {
      XP[((size_t)b * SEQ + t) * 4 + (l - 16)] = acc;
    } else if (l < 36) {
      CD[((size_t)b * SEQ + t) * 16 + (l - 20)] = acc;
    }
  }
  __syncthreads();

  // Phase B: one 64-step chunk aggregate. thread -> d = tid>>2, n0 = 4*(tid&3)
  const int d  = tid >> 2;
  const int n0 = (tid & 3) << 2;
  float Av4[4];
  {
    const float4 a = *(const float4*)(A_log + d * 16 + n0);
    Av4[0] = -expf(a.x); Av4[1] = -expf(a.y);
    Av4[2] = -expf(a.z); Av4[3] = -expf(a.w);
  }
  float P0 = 1.f, P1 = 1.f, P2 = 1.f, P3 = 1.f;
  float q0 = 0.f, q1 = 0.f, q2 = 0.f, q3 = 0.f;
#pragma unroll
  for (int s = 0; s < 64; ++s) {
    const float dtv = dts[s * 64 + d];
    const float xdt = xds[s * 64 + d];
    const float4 Bq = *(const float4*)(&Bs[s * 16 + n0]);
    float dA;
    dA = dtv * Av4[0]; q0 = fmaf(q0, dA, xdt * Bq.x); P0 *= dA;
    dA = dtv * Av4[1]; q1 = fmaf(q1, dA, xdt * Bq.y); P1 *= dA;
    dA = dtv * Av4[2]; q2 = fmaf(q2, dA, xdt * Bq.z); P2 *= dA;
    dA = dtv * Av4[3]; q3 = fmaf(q3, dA, xdt * Bq.w); P3 *= dA;
  }
  const int c = blockIdx.x & 63;
  float4* dst = (float4*)(Pp + ((size_t)b * 64 + c) * 1024 + d * 16 + n0);
  dst[0] = make_float4(P0, q0, P1, q1);
  dst[1] = make_float4(P2, q2, P3, q3);
}

// ------------- Phase 2: serial carry; compact Hin ---------------------------
__global__ __launch_bounds__(256) void ssm_carry(const float2* __restrict__ Pp,
                                                 float* __restrict__ Hin) {
  const int b = blockIdx.x >> 2;
  const int cell = ((blockIdx.x & 3) << 8) + threadIdx.x;
  const float2* base = Pp + (size_t)b * (64 * 1024) + cell;
  float* hout = Hin + (size_t)b * (64 * 1024) + cell;
  float H = 0.f;
#pragma unroll
  for (int g = 0; g < 4; ++g) {
    float2 v[16];
#pragma unroll
    for (int j = 0; j < 16; ++j) v[j] = base[(size_t)(g * 16 + j) * 1024];
#pragma unroll
    for (int j = 0; j < 16; ++j) {
      hout[(size_t)(g * 16 + j) * 1024] = H;
      H = fmaf(v[j].x, H, v[j].y);
    }
  }
}

// ------------- Phase 3: scan; dt from XP; nt hidden; 64-step chunks --------
__global__ __launch_bounds__(256, 6) void ssm_scan(
    const float* __restrict__ ws, const float* __restrict__ x,
    const float* __restrict__ Wdt, const float* __restrict__ bdt,
    const float* __restrict__ A_log, const float* __restrict__ Dp,
    float* __restrict__ out, float* __restrict__ hidden) {
  __shared__ __align__(16) float x_lds[64 * 64];   // [t][d] 16 KB
  __shared__ __align__(16) float Bs[64 * 16];      // [t][n]  4 KB
  __shared__ __align__(16) float Cs[64 * 16];      // [t][n]  4 KB
  __shared__ __align__(16) float xq_lds[64 * 4];   // [t][r]  1 KB
  const int tid  = threadIdx.x;
  const int w    = tid >> 6;            // wave = d-quarter dq
  const int lane = tid & 63;
  const int b  = blockIdx.x >> 6;
  const int c  = blockIdx.x & 63;
  const int t0 = c << 6;
  const int dl = lane >> 2;             // d within quarter
  const int nq = lane & 3;              // n-quad
  const int d  = (w << 4) + dl;

  // ---- stage: x (each wave: its 16-t slice); B,C (1/4 each); XP (wave 0) --
  const float* xg = x + ((size_t)b * SEQ + t0 + (w << 4)) * 64;
  const int srcoff = (lane >> 4) * 64 + (lane & 15) * 4;  // t-row + 16B piece
#pragma unroll
  for (int k = 0; k < 4; ++k)
    async_copy16(xg + k * 256 + srcoff, x_lds + ((w << 4) + (k << 2)) * 64 + lane * 4);
  const float* Bg  = ws +           ((size_t)b * SEQ + t0) * 16;
  const float* Cg  = ws + 2097152 + ((size_t)b * SEQ + t0) * 16;
  const float* XPg = ws + 4194304 + ((size_t)b * SEQ + t0) * 4;
  async_copy16(Bg + (w << 8) + lane * 4, Bs + (w << 8) + lane * 4);
  async_copy16(Cg + (w << 8) + lane * 4, Cs + (w << 8) + lane * 4);
  if (w == 0) async_copy16(XPg + lane * 4, xq_lds + lane * 4);

  float Av[4];
  {
    const float4 a = *(const float4*)(A_log + d * 16 + (nq << 2));
    Av[0] = -expf(a.x); Av[1] = -expf(a.y);
    Av[2] = -expf(a.z); Av[3] = -expf(a.w);
  }
  const float Dpv = Dp[d];
  const float4 wdtv = ((const float4*)Wdt)[d];
  const float bdtv = bdt[d];

  float h[4];
  {
    const f32x4 v = *(const f32x4*)(ws + 8912896 +
        ((size_t)b * 64 + c) * 1024 + d * 16 + (nq << 2));
    h[0] = v.x; h[1] = v.y; h[2] = v.z; h[3] = v.w;
  }

  // lane writes 16B at byte offset 16*lane -> wave-step writes contiguous 1KB
  float* hidp = hidden + ((size_t)b * SEQ + t0) * 1024 + (w << 8) + (lane << 2);
  float* outp = out + ((size_t)b * SEQ + t0) * 64 + d;

  asm volatile("s_waitcnt vmcnt(0)" ::: "memory");
  __syncthreads();

  // ---- body: LDS reads + VALU + stores (no global loads, no vmcnt) -------
  for (int T = 0; T < CSTEPS; T += 8) {
    float x8[8], dt8[8];
#pragma unroll
    for (int j = 0; j < 8; ++j) {
      x8[j] = x_lds[(T + j) * 64 + d];
      const f32x4 xp = *(const f32x4*)(xq_lds + (T + j) * 4);
      float dtv = bdtv;
      dtv = fmaf(wdtv.x, xp.x, dtv);
      dtv = fmaf(wdtv.y, xp.y, dtv);
      dtv = fmaf(wdtv.z, xp.z, dtv);
      dtv = fmaf(wdtv.w, xp.w, dtv);
      dt8[j] = dtv;
    }
#pragma unroll
    for (int j = 0; j < 8; ++j) {
      const int t = T + j;
      const float dtv = dt8[j];
      const float xv  = x8[j];
      const float xd  = xv * dtv;
      const float4 Bq = *(const float4*)(Bs + t * 16 + (nq << 2));
      const float4 Cq = *(const float4*)(Cs + t * 16 + (nq << 2));
      float y, hv;
      hv = __builtin_amdgcn_fmed3f(fmaf(h[0], dtv * Av[0], xd * Bq.x), -1e6f, 1e6f);
      h[0] = hv; y = hv * Cq.x;
      hv = __builtin_amdgcn_fmed3f(fmaf(h[1], dtv * Av[1], xd * Bq.y), -1e6f, 1e6f);
      h[1] = hv; y = fmaf(hv, Cq.y, y);
      hv = __builtin_amdgcn_fmed3f(fmaf(h[2], dtv * Av[2], xd * Bq.z), -1e6f, 1e6f);
      h[2] = hv; y = fmaf(hv, Cq.z, y);
      hv = __builtin_amdgcn_fmed3f(fmaf(h[3], dtv * Av[3], xd * Bq.w), -1e6f, 1e6f);
      h[3] = hv; y = fmaf(hv, Cq.w, y);
      f32x4 hvq;
      hvq.x = h[0]; hvq.y = h[1]; hvq.z = h[2]; hvq.w = h[3];
      __builtin_nontemporal_store(hvq, (f32x4*)(hidp + (size_t)t * 1024));
      y = qp_add_b1(y);   // quad_perm [1,0,3,2]
      y = qp_add_4e(y);   // quad_perm [2,3,0,1] -> full quad sum
      if (nq == 0) outp[(size_t)t * 64] = fmaf(Dpv, xv, y);   // normal store
    }
  }
}

extern "C" void kernel_launch(void* const* d_in, const int* in_sizes, int n_in,
                              void* d_out, int out_size, void* d_ws, size_t ws_size,
                              hipStream_t stream) {
  (void)in_sizes; (void)n_in; (void)out_size; (void)ws_size;
  const float* x     = (const float*)d_in[0];
  const float* Wx    = (const float*)d_in[1];
  const float* bx    = (const float*)d_in[2];
  const float* Wdt   = (const float*)d_in[3];
  const float* bdt   = (const float*)d_in[4];
  const float* A_log = (const float*)d_in[5];
  const float* Dp    = (const float*)d_in[6];
  float* out    = (float*)d_out;
  float* hidden = out + (size_t)NB * SEQ * 64;
  float* ws     = (float*)d_ws;
  float2* Pp    = (float2*)(ws + 4718592);
  float*  Hin   = ws + 8912896;

  ssm_prep<<<dim3(2048), dim3(256), 0, stream>>>(x, Wx, bx, Wdt, bdt, A_log, ws, Pp);
  ssm_carry<<<dim3(128), dim3(256), 0, stream>>>(Pp, Hin);
  ssm_scan<<<dim3(2048), dim3(256), 0, stream>>>(ws, x, Wdt, bdt, A_log, Dp, out, hidden);
}